// Round 4
// baseline (255.531 us; speedup 1.0000x reference)
//
#include <hip/hip_runtime.h>

// Problem constants (L=16, K=2, V=2)
constexpr int S_ = 1 << 16;   // 65536 states
constexpr int R_ = 1 << 12;   // 4096 reduced states
constexpr int D_ = 16;        // candidates per reduced state
constexpr int B_ = 512;       // batch
constexpr int BLOCK = 256;    // 4 waves
constexpr int RPT  = 4;       // r per thread (float4 granularity)
constexpr int RPB  = BLOCK * RPT;   // 1024 r per block
constexpr int CHUNKS = R_ / RPB;    // 4 chunks per batch row

typedef float v4f __attribute__((ext_vector_type(4)));

// lut[s] depends only on t(s) = ((s+1)*s >> 7) & 255 (256 distinct rows).
// Scatter into a 256-entry table; equal-t writers store identical values.
__global__ __launch_bounds__(256) void build_tab_kernel(
    const float* __restrict__ lut, float2* __restrict__ tab)
{
    const unsigned s = blockIdx.x * 256u + threadIdx.x;
    const unsigned t = (((s + 1u) * s) >> 7) & 255u;
    tab[t] = make_float2(lut[2 * s], lut[2 * s + 1]);
}

// R2/R3 lesson: VGPR_Count stayed 32 — both the explicit v[16] array and
// sched_barrier(0) were defeated; the compiler re-fused each load with its
// consumer (~1 KB in flight/wave -> 2.5 TB/s latency-bound). Fix: ONE
// inline-asm block issuing all 16 global_load_dwordx4 (SGPR base, 32-bit
// voffset += 0x4000 between loads; 16 KB stride exceeds the 13-bit imm),
// ending with s_waitcnt vmcnt(0) inside the block. "=&v" early-clobber
// outputs force 64 payload VGPRs live. Verify: VGPR_Count ~100-128.
__global__ __launch_bounds__(BLOCK, 4) void trellis_kernel(
    const float*  __restrict__ cost,   // (B, S)
    const float*  __restrict__ orig,   // (B, 2)
    const float2* __restrict__ tab,    // (256,) lut rows by t
    float*        __restrict__ prev_state_out, // (B, R) as float
    float*        __restrict__ new_cost)       // (B, S)
{
    __shared__ float lds_bv[RPB];      // 4 KB
    __shared__ float lds_err[256];     // 1 KB

    const int b      = blockIdx.x / CHUNKS;
    const int rchunk = blockIdx.x % CHUNKS;
    const int r0     = rchunk * RPB;
    const int tid    = threadIdx.x;

    const float  o0 = orig[2 * b + 0];
    const float  o1 = orig[2 * b + 1];
    const float2 tv = tab[tid];

    // per-b squared-error table (256 entries, one per thread)
    {
        const float e0 = tv.x - o0, e1 = tv.y - o1;
        lds_err[tid] = e0 * e0 + e1 * e1;
    }

    // ---- phase 1: 16 d-strided float4 loads, forced in flight via asm ----
    const float* sbase = cost + (size_t)b * S_ + r0;   // wave-uniform (SGPR)
    unsigned voff = (unsigned)tid * 16u;               // per-lane byte offset
    v4f c0, c1, c2, c3, c4, c5, c6, c7, c8, c9, c10, c11, c12, c13, c14, c15;
    asm volatile(
        "global_load_dwordx4 %[c0], %[off], %[sb]\n\t"
        "v_add_u32 %[off], 0x4000, %[off]\n\t"
        "global_load_dwordx4 %[c1], %[off], %[sb]\n\t"
        "v_add_u32 %[off], 0x4000, %[off]\n\t"
        "global_load_dwordx4 %[c2], %[off], %[sb]\n\t"
        "v_add_u32 %[off], 0x4000, %[off]\n\t"
        "global_load_dwordx4 %[c3], %[off], %[sb]\n\t"
        "v_add_u32 %[off], 0x4000, %[off]\n\t"
        "global_load_dwordx4 %[c4], %[off], %[sb]\n\t"
        "v_add_u32 %[off], 0x4000, %[off]\n\t"
        "global_load_dwordx4 %[c5], %[off], %[sb]\n\t"
        "v_add_u32 %[off], 0x4000, %[off]\n\t"
        "global_load_dwordx4 %[c6], %[off], %[sb]\n\t"
        "v_add_u32 %[off], 0x4000, %[off]\n\t"
        "global_load_dwordx4 %[c7], %[off], %[sb]\n\t"
        "v_add_u32 %[off], 0x4000, %[off]\n\t"
        "global_load_dwordx4 %[c8], %[off], %[sb]\n\t"
        "v_add_u32 %[off], 0x4000, %[off]\n\t"
        "global_load_dwordx4 %[c9], %[off], %[sb]\n\t"
        "v_add_u32 %[off], 0x4000, %[off]\n\t"
        "global_load_dwordx4 %[c10], %[off], %[sb]\n\t"
        "v_add_u32 %[off], 0x4000, %[off]\n\t"
        "global_load_dwordx4 %[c11], %[off], %[sb]\n\t"
        "v_add_u32 %[off], 0x4000, %[off]\n\t"
        "global_load_dwordx4 %[c12], %[off], %[sb]\n\t"
        "v_add_u32 %[off], 0x4000, %[off]\n\t"
        "global_load_dwordx4 %[c13], %[off], %[sb]\n\t"
        "v_add_u32 %[off], 0x4000, %[off]\n\t"
        "global_load_dwordx4 %[c14], %[off], %[sb]\n\t"
        "v_add_u32 %[off], 0x4000, %[off]\n\t"
        "global_load_dwordx4 %[c15], %[off], %[sb]\n\t"
        "s_waitcnt vmcnt(0)"
        : [c0]"=&v"(c0),  [c1]"=&v"(c1),  [c2]"=&v"(c2),  [c3]"=&v"(c3),
          [c4]"=&v"(c4),  [c5]"=&v"(c5),  [c6]"=&v"(c6),  [c7]"=&v"(c7),
          [c8]"=&v"(c8),  [c9]"=&v"(c9),  [c10]"=&v"(c10), [c11]"=&v"(c11),
          [c12]"=&v"(c12), [c13]"=&v"(c13), [c14]"=&v"(c14), [c15]"=&v"(c15),
          [off]"+v"(voff)
        : [sb]"s"(sbase)
        : "memory");

    // ---- min/argmin over d in registers; strict <: first-min wins ----
    float bva = c0[0], bvb = c0[1], bvc = c0[2], bvd = c0[3];
    int bia = 0, bib = 0, bic = 0, bid_ = 0;
#define TRELLIS_STEP(d, cc) \
    if (cc[0] < bva) { bva = cc[0]; bia  = d; } \
    if (cc[1] < bvb) { bvb = cc[1]; bib  = d; } \
    if (cc[2] < bvc) { bvc = cc[2]; bic  = d; } \
    if (cc[3] < bvd) { bvd = cc[3]; bid_ = d; }
    TRELLIS_STEP(1,  c1)  TRELLIS_STEP(2,  c2)  TRELLIS_STEP(3,  c3)
    TRELLIS_STEP(4,  c4)  TRELLIS_STEP(5,  c5)  TRELLIS_STEP(6,  c6)
    TRELLIS_STEP(7,  c7)  TRELLIS_STEP(8,  c8)  TRELLIS_STEP(9,  c9)
    TRELLIS_STEP(10, c10) TRELLIS_STEP(11, c11) TRELLIS_STEP(12, c12)
    TRELLIS_STEP(13, c13) TRELLIS_STEP(14, c14) TRELLIS_STEP(15, c15)
#undef TRELLIS_STEP

    // state_candidates[r][d] == r + (d<<12) exactly (closed form; no gather)
    const int r = r0 + tid * RPT;
    *(float4*)(prev_state_out + (size_t)b * R_ + r) =
        make_float4((float)(r     + (bia  << 12)),
                    (float)(r + 1 + (bib  << 12)),
                    (float)(r + 2 + (bic  << 12)),
                    (float)(r + 3 + (bid_ << 12)));

    *(float4*)(lds_bv + tid * RPT) = make_float4(bva, bvb, bvc, bvd);
    __syncthreads();

    // ---- phase 2: new_cost[b,s] = err[t(s)] + bv[s>>4]; contiguous 64 KB ----
    const int s_base = r0 << 4;    // r0 * D_
    float* outb = new_cost + (size_t)b * S_ + s_base;
    #pragma unroll
    for (int it = 0; it < (RPB * D_) / (BLOCK * 4); ++it) {   // 16 iters
        const int flat = it * (BLOCK * 4) + tid * 4;
        const unsigned s = (unsigned)(s_base + flat);
        const float bvv = lds_bv[flat >> 4];   // 4-lane same-addr broadcast
        float4 out;
        out.x = lds_err[(((s + 1u) * (s + 0u)) >> 7) & 255u] + bvv;
        out.y = lds_err[(((s + 2u) * (s + 1u)) >> 7) & 255u] + bvv;
        out.z = lds_err[(((s + 3u) * (s + 2u)) >> 7) & 255u] + bvv;
        out.w = lds_err[(((s + 4u) * (s + 3u)) >> 7) & 255u] + bvv;
        *(float4*)(outb + flat) = out;
    }
}

extern "C" void kernel_launch(void* const* d_in, const int* in_sizes, int n_in,
                              void* d_out, int out_size, void* d_ws, size_t ws_size,
                              hipStream_t stream) {
    const float* lut  = (const float*)d_in[0];   // training_lut (S,2)
    const float* cost = (const float*)d_in[1];   // cost (B,S)
    const float* orig = (const float*)d_in[2];   // orig_seq_part (B,2)
    // d_in[3] = state_candidates — closed form r + (d<<12), not needed on device

    float* prev_state = (float*)d_out;                      // output 0: (B,R)
    float* new_cost   = (float*)d_out + (size_t)B_ * R_;    // output 1: (B,S)
    float2* tab       = (float2*)d_ws;                      // 256 entries (2 KB)

    hipLaunchKernelGGL(build_tab_kernel, dim3(S_ / 256), dim3(256), 0, stream,
                       lut, tab);
    hipLaunchKernelGGL(trellis_kernel, dim3(B_ * CHUNKS), dim3(BLOCK), 0, stream,
                       cost, orig, tab, prev_state, new_cost);
}